// Round 1
// baseline (191.072 us; speedup 1.0000x reference)
//
#include <hip/hip_runtime.h>

// SphericalEmbedding: positions [32,1024,3] f32, W [81,2048] f32 -> out [32768, 2048] f32
// Round 1: fused fp32 tiled kernel. SH per point into LDS (transposed), then
// register-tiled GEMM: 32 points x 256 channels per block, 4x8 acc per thread.

#define NPT_TILE 32      // points per block  (BM)
#define NCH_TILE 256     // channels per block (BN)
#define TPB      256

// ---- compile-time normalization table ----------------------------------
constexpr double PI_D = 3.14159265358979323846;
constexpr double csqrt_c(double v) {
  if (v <= 0.0) return 0.0;
  double g = v < 1.0 ? 1.0 : v;
  for (int i = 0; i < 100; ++i) g = 0.5 * (g + v / g);
  return g;
}
struct Norms { float c[81]; };
constexpr Norms make_norms() {
  Norms n{};
  for (int l = 0; l <= 8; ++l) {
    for (int m = -l; m <= l; ++m) {
      int am = m < 0 ? -m : m;
      double fr = 1.0;                       // (l+am)! / (l-am)!
      for (int i = l - am + 1; i <= l + am; ++i) fr *= (double)i;
      double v = csqrt_c((2.0 * l + 1.0) / (4.0 * PI_D) / fr);
      if (m < 0 && (am & 1)) v = -v;         // (-1)^{|m|} for m<0
      n.c[l * l + l + m] = (float)v;
    }
  }
  return n;
}
constexpr Norms NORMS = make_norms();

__global__ __launch_bounds__(TPB)
void sph_embed_kernel(const float* __restrict__ pos,
                      const float* __restrict__ W,
                      float* __restrict__ out,
                      int nch)
{
  __shared__ float sh[81 * NPT_TILE];        // sh[k][p], transposed, 10.4 KB
  const int nblk = blockIdx.x;               // channel tile index
  const int mblk = blockIdx.y;               // point tile index
  const int tid  = threadIdx.x;
  const int tx   = tid & 31;                 // channel-thread (8 channels each)
  const int ty   = tid >> 5;                 // point-thread   (4 points each)

  // ---- phase 1: compute 81 real spherical harmonics for 32 points -------
  if (tid < NPT_TILE) {
    const int gp = mblk * NPT_TILE + tid;
    const float px = pos[gp * 3 + 0];
    const float py = pos[gp * 3 + 1];
    const float pz = pos[gp * 3 + 2];
    const float r   = sqrtf(px * px + py * py + pz * pz);
    const float inv = 1.0f / (r + 1e-8f);
    const float xn = px * inv, yn = py * inv, zn = pz * inv;
    const float x = fminf(1.0f, fmaxf(-1.0f, zn));     // cos(theta)
    const float s = sqrtf(fmaxf(0.0f, 1.0f - x * x));  // sin(theta) >= 0
    const float rho = sqrtf(xn * xn + yn * yn);
    const float c1  = rho > 0.0f ? xn / rho : 1.0f;    // cos(phi)

    // cos(m*phi) via Chebyshev recurrence
    float cm[9];
    cm[0] = 1.0f;
    cm[1] = c1;
#pragma unroll
    for (int m = 2; m <= 8; ++m) cm[m] = 2.0f * c1 * cm[m - 1] - cm[m - 2];

    // associated Legendre P[l][m] (Condon-Shortley), same recurrence as ref
    float P[9][9];
#pragma unroll
    for (int m = 0; m <= 8; ++m) {
      if (m == 0) P[0][0] = 1.0f;
      else        P[m][m] = -(float)(2 * m - 1) * s * P[m - 1][m - 1];
      if (m + 1 <= 8) P[m + 1][m] = (float)(2 * m + 1) * x * P[m][m];
#pragma unroll
      for (int l = m + 2; l <= 8; ++l)
        P[l][m] = ((float)(2 * l - 1) * x * P[l - 1][m]
                   - (float)(l + m - 1) * P[l - 2][m]) / (float)(l - m);
    }

    // Y[idx] = NORM[idx] * P[l][|m|] * cos(|m| phi), idx = l^2 + l + m
#pragma unroll
    for (int l = 0; l <= 8; ++l) {
#pragma unroll
      for (int m = -l; m <= l; ++m) {
        const int am  = m < 0 ? -m : m;
        const int idx = l * l + l + m;
        sh[idx * NPT_TILE + tid] = NORMS.c[idx] * P[l][am] * cm[am];
      }
    }
  }
  __syncthreads();

  // ---- phase 2: GEMM tile, 4 points x 8 channels per thread --------------
  const float* Wp = W + nblk * NCH_TILE + tx * 8;
  float acc[4][8];
#pragma unroll
  for (int p = 0; p < 4; ++p)
#pragma unroll
    for (int j = 0; j < 8; ++j) acc[p][j] = 0.0f;

#pragma unroll 3
  for (int k = 0; k < 81; ++k) {
    const float4 w0 = *reinterpret_cast<const float4*>(Wp + (size_t)k * nch);
    const float4 w1 = *reinterpret_cast<const float4*>(Wp + (size_t)k * nch + 4);
    const float4 s4 = *reinterpret_cast<const float4*>(&sh[k * NPT_TILE + ty * 4]);
    const float sv[4] = {s4.x, s4.y, s4.z, s4.w};
    const float wv[8] = {w0.x, w0.y, w0.z, w0.w, w1.x, w1.y, w1.z, w1.w};
#pragma unroll
    for (int p = 0; p < 4; ++p)
#pragma unroll
      for (int j = 0; j < 8; ++j)
        acc[p][j] = fmaf(sv[p], wv[j], acc[p][j]);
  }

  // ---- epilogue: coalesced float4 stores ---------------------------------
  const size_t obase = (size_t)(mblk * NPT_TILE + ty * 4) * nch
                     + (size_t)nblk * NCH_TILE + (size_t)tx * 8;
#pragma unroll
  for (int p = 0; p < 4; ++p) {
    float4 o0 = {acc[p][0], acc[p][1], acc[p][2], acc[p][3]};
    float4 o1 = {acc[p][4], acc[p][5], acc[p][6], acc[p][7]};
    *reinterpret_cast<float4*>(out + obase + (size_t)p * nch)     = o0;
    *reinterpret_cast<float4*>(out + obase + (size_t)p * nch + 4) = o1;
  }
}

extern "C" void kernel_launch(void* const* d_in, const int* in_sizes, int n_in,
                              void* d_out, int out_size, void* d_ws, size_t ws_size,
                              hipStream_t stream) {
  const float* pos = (const float*)d_in[0];   // [npts, 3]
  const float* W   = (const float*)d_in[1];   // [81, nch]
  float*       out = (float*)d_out;           // [npts, nch]
  const int npts = in_sizes[0] / 3;           // 32768
  const int nch  = in_sizes[1] / 81;          // 2048

  dim3 grid(nch / NCH_TILE, npts / NPT_TILE); // (8, 1024)
  sph_embed_kernel<<<grid, TPB, 0, stream>>>(pos, W, out, nch);
}

// Round 2
// 55.684 us; speedup vs baseline: 3.4314x; 3.4314x over previous
//
#include <hip/hip_runtime.h>

// SphericalEmbedding round 2: bf16 MFMA GEMM.
//   pre-kernel:  W [81,2048] f32 -> WT [2048][96] bf16 (zero-padded K) in d_ws
//   main kernel: 128 pts x 128 ch per block; harmonics -> bf16 A-tile in LDS;
//                per wave 64x64 C-tile via mfma_f32_16x16x32_bf16, K=96 (3 steps).
// Fallback to the round-1 fp32 kernel if ws_size < 384 KB.

typedef __attribute__((ext_vector_type(8))) short bf16x8;
typedef __attribute__((ext_vector_type(4))) float f32x4;

#define BM 128
#define BN 128
#define LDA 104          // A row stride in bf16: 208 B = 52 dwords -> 2-way bank aliasing (free)
#define KPAD 96

// ---- compile-time normalization table ----------------------------------
constexpr double PI_D = 3.14159265358979323846;
constexpr double csqrt_c(double v) {
  if (v <= 0.0) return 0.0;
  double g = v < 1.0 ? 1.0 : v;
  for (int i = 0; i < 100; ++i) g = 0.5 * (g + v / g);
  return g;
}
struct Norms { float c[81]; };
constexpr Norms make_norms() {
  Norms n{};
  for (int l = 0; l <= 8; ++l)
    for (int m = -l; m <= l; ++m) {
      int am = m < 0 ? -m : m;
      double fr = 1.0;
      for (int i = l - am + 1; i <= l + am; ++i) fr *= (double)i;
      double v = csqrt_c((2.0 * l + 1.0) / (4.0 * PI_D) / fr);
      if (m < 0 && (am & 1)) v = -v;
      n.c[l * l + l + m] = (float)v;
    }
  return n;
}
constexpr Norms NORMS = make_norms();

__device__ __forceinline__ unsigned f2bf(float f) {   // RTN-even f32 -> bf16 bits
  unsigned u = __float_as_uint(f);
  return (u + 0x7fffu + ((u >> 16) & 1u)) >> 16;
}

// ---- pre-kernel: W f32 [81][nch] -> WT bf16 [nch][96] (padded) ---------
__global__ __launch_bounds__(256)
void wt_convert_kernel(const float* __restrict__ W, unsigned short* __restrict__ WT, int nch) {
  const int t = blockIdx.x * 256 + threadIdx.x;    // t in [0, nch*12)
  if (t >= nch * 12) return;
  const int kg = t / nch;                          // k-group of 8 (0..11)
  const int c  = t - kg * nch;                     // lanes -> consecutive c (coalesced)
  unsigned short v[8];
#pragma unroll
  for (int j = 0; j < 8; ++j) {
    const int k = kg * 8 + j;
    v[j] = (k < 81) ? (unsigned short)f2bf(W[(size_t)k * nch + c]) : (unsigned short)0;
  }
  unsigned* dst = reinterpret_cast<unsigned*>(WT + (size_t)c * KPAD + kg * 8);
#pragma unroll
  for (int j = 0; j < 4; ++j)
    dst[j] = (unsigned)v[2 * j] | ((unsigned)v[2 * j + 1] << 16);
}

// ---- main MFMA kernel ---------------------------------------------------
__global__ __launch_bounds__(256)
void sph_mfma_kernel(const float* __restrict__ pos,
                     const unsigned short* __restrict__ WT,
                     float* __restrict__ out, int nch)
{
  __shared__ unsigned short A[BM * LDA];           // 26.6 KB, bf16 harmonics tile
  const int tid  = threadIdx.x;
  const int lane = tid & 63;
  const int wid  = tid >> 6;                       // 4 waves: 2(M) x 2(N)
  const int wm   = wid >> 1, wn = wid & 1;
  const int l15  = lane & 15, l4 = lane >> 4;
  const int mblk = blockIdx.y, nblk = blockIdx.x;

  // ---- phase 1: harmonics for 128 points -> bf16 rows in LDS -----------
  if (tid < BM) {
    const int gp = mblk * BM + tid;
    const float px = pos[gp * 3 + 0];
    const float py = pos[gp * 3 + 1];
    const float pz = pos[gp * 3 + 2];
    const float r   = sqrtf(px * px + py * py + pz * pz);
    const float inv = 1.0f / (r + 1e-8f);
    const float xn = px * inv, yn = py * inv, zn = pz * inv;
    const float x = fminf(1.0f, fmaxf(-1.0f, zn));     // cos(theta)
    const float s = sqrtf(fmaxf(0.0f, 1.0f - x * x));  // sin(theta)
    const float rho = sqrtf(xn * xn + yn * yn);
    const float c1  = rho > 0.0f ? xn / rho : 1.0f;    // cos(phi)

    float cm[9];
    cm[0] = 1.0f; cm[1] = c1;
#pragma unroll
    for (int m = 2; m <= 8; ++m) cm[m] = 2.0f * c1 * cm[m - 1] - cm[m - 2];

    float P[9][9];
#pragma unroll
    for (int m = 0; m <= 8; ++m) {
      if (m == 0) P[0][0] = 1.0f;
      else        P[m][m] = -(float)(2 * m - 1) * s * P[m - 1][m - 1];
      if (m + 1 <= 8) P[m + 1][m] = (float)(2 * m + 1) * x * P[m][m];
#pragma unroll
      for (int l = m + 2; l <= 8; ++l)
        P[l][m] = ((float)(2 * l - 1) * x * P[l - 1][m]
                   - (float)(l + m - 1) * P[l - 2][m]) / (float)(l - m);
    }

    float y[KPAD];
#pragma unroll
    for (int l = 0; l <= 8; ++l)
#pragma unroll
      for (int m = -l; m <= l; ++m) {
        const int am  = m < 0 ? -m : m;
        const int idx = l * l + l + m;
        y[idx] = NORMS.c[idx] * P[l][am] * cm[am];
      }
#pragma unroll
    for (int i = 81; i < KPAD; ++i) y[i] = 0.0f;

    unsigned* arow = reinterpret_cast<unsigned*>(&A[tid * LDA]);
#pragma unroll
    for (int i = 0; i < KPAD / 2; ++i)
      arow[i] = f2bf(y[2 * i]) | (f2bf(y[2 * i + 1]) << 16);
  }

  // ---- B fragments: direct 16B global loads from WT (L2-resident) ------
  bf16x8 bfrag[3][4];
  const unsigned short* wt_base =
      WT + (size_t)(nblk * BN + wn * 64 + l15) * KPAD + l4 * 8;
#pragma unroll
  for (int kk = 0; kk < 3; ++kk)
#pragma unroll
    for (int nr = 0; nr < 4; ++nr)
      bfrag[kk][nr] = *reinterpret_cast<const bf16x8*>(wt_base + (size_t)nr * 16 * KPAD + kk * 32);

  __syncthreads();

  // ---- MFMA: 3 k-steps, per wave 4x4 16x16 C sub-tiles ------------------
  f32x4 acc[4][4] = {};
#pragma unroll
  for (int kk = 0; kk < 3; ++kk) {
    bf16x8 afrag[4];
#pragma unroll
    for (int mr = 0; mr < 4; ++mr)
      afrag[mr] = *reinterpret_cast<const bf16x8*>(
          &A[(wm * 64 + mr * 16 + l15) * LDA + kk * 32 + l4 * 8]);
#pragma unroll
    for (int mr = 0; mr < 4; ++mr)
#pragma unroll
      for (int nr = 0; nr < 4; ++nr)
        acc[mr][nr] = __builtin_amdgcn_mfma_f32_16x16x32_bf16(
            afrag[mr], bfrag[kk][nr], acc[mr][nr], 0, 0, 0);
  }

  // ---- epilogue: C[row = (l>>4)*4+reg (+16*mr), col = l&15 (+16*nr)] ----
  const size_t row0 = (size_t)mblk * BM + wm * 64 + l4 * 4;
  const size_t col0 = (size_t)nblk * BN + wn * 64 + l15;
#pragma unroll
  for (int mr = 0; mr < 4; ++mr)
#pragma unroll
    for (int r = 0; r < 4; ++r) {
      float* orow = out + (row0 + mr * 16 + r) * nch + col0;
#pragma unroll
      for (int nr = 0; nr < 4; ++nr)
        orow[nr * 16] = acc[mr][nr][r];
    }
}

// ======================= round-1 fp32 fallback ==========================
#define NPT_TILE 32
#define NCH_TILE 256
#define TPB      256

__global__ __launch_bounds__(TPB)
void sph_embed_kernel(const float* __restrict__ pos,
                      const float* __restrict__ W,
                      float* __restrict__ out, int nch)
{
  __shared__ float sh[81 * NPT_TILE];
  const int nblk = blockIdx.x, mblk = blockIdx.y, tid = threadIdx.x;
  const int tx = tid & 31, ty = tid >> 5;
  if (tid < NPT_TILE) {
    const int gp = mblk * NPT_TILE + tid;
    const float px = pos[gp * 3 + 0], py = pos[gp * 3 + 1], pz = pos[gp * 3 + 2];
    const float r = sqrtf(px * px + py * py + pz * pz);
    const float inv = 1.0f / (r + 1e-8f);
    const float xn = px * inv, yn = py * inv, zn = pz * inv;
    const float x = fminf(1.0f, fmaxf(-1.0f, zn));
    const float s = sqrtf(fmaxf(0.0f, 1.0f - x * x));
    const float rho = sqrtf(xn * xn + yn * yn);
    const float c1 = rho > 0.0f ? xn / rho : 1.0f;
    float cm[9]; cm[0] = 1.0f; cm[1] = c1;
#pragma unroll
    for (int m = 2; m <= 8; ++m) cm[m] = 2.0f * c1 * cm[m - 1] - cm[m - 2];
    float P[9][9];
#pragma unroll
    for (int m = 0; m <= 8; ++m) {
      if (m == 0) P[0][0] = 1.0f;
      else        P[m][m] = -(float)(2 * m - 1) * s * P[m - 1][m - 1];
      if (m + 1 <= 8) P[m + 1][m] = (float)(2 * m + 1) * x * P[m][m];
#pragma unroll
      for (int l = m + 2; l <= 8; ++l)
        P[l][m] = ((float)(2 * l - 1) * x * P[l - 1][m]
                   - (float)(l + m - 1) * P[l - 2][m]) / (float)(l - m);
    }
#pragma unroll
    for (int l = 0; l <= 8; ++l)
#pragma unroll
      for (int m = -l; m <= l; ++m) {
        const int am = m < 0 ? -m : m;
        const int idx = l * l + l + m;
        sh[idx * NPT_TILE + tid] = NORMS.c[idx] * P[l][am] * cm[am];
      }
  }
  __syncthreads();
  const float* Wp = W + nblk * NCH_TILE + tx * 8;
  float acc[4][8];
#pragma unroll
  for (int p = 0; p < 4; ++p)
#pragma unroll
    for (int j = 0; j < 8; ++j) acc[p][j] = 0.0f;
#pragma unroll 3
  for (int k = 0; k < 81; ++k) {
    const float4 w0 = *reinterpret_cast<const float4*>(Wp + (size_t)k * nch);
    const float4 w1 = *reinterpret_cast<const float4*>(Wp + (size_t)k * nch + 4);
    const float4 s4 = *reinterpret_cast<const float4*>(&sh[k * NPT_TILE + ty * 4]);
    const float sv[4] = {s4.x, s4.y, s4.z, s4.w};
    const float wv[8] = {w0.x, w0.y, w0.z, w0.w, w1.x, w1.y, w1.z, w1.w};
#pragma unroll
    for (int p = 0; p < 4; ++p)
#pragma unroll
      for (int j = 0; j < 8; ++j)
        acc[p][j] = fmaf(sv[p], wv[j], acc[p][j]);
  }
  const size_t obase = (size_t)(mblk * NPT_TILE + ty * 4) * nch
                     + (size_t)nblk * NCH_TILE + (size_t)tx * 8;
#pragma unroll
  for (int p = 0; p < 4; ++p) {
    float4 o0 = {acc[p][0], acc[p][1], acc[p][2], acc[p][3]};
    float4 o1 = {acc[p][4], acc[p][5], acc[p][6], acc[p][7]};
    *reinterpret_cast<float4*>(out + obase + (size_t)p * nch)     = o0;
    *reinterpret_cast<float4*>(out + obase + (size_t)p * nch + 4) = o1;
  }
}

extern "C" void kernel_launch(void* const* d_in, const int* in_sizes, int n_in,
                              void* d_out, int out_size, void* d_ws, size_t ws_size,
                              hipStream_t stream) {
  const float* pos = (const float*)d_in[0];   // [npts, 3]
  const float* W   = (const float*)d_in[1];   // [81, nch]
  float*       out = (float*)d_out;           // [npts, nch]
  const int npts = in_sizes[0] / 3;           // 32768
  const int nch  = in_sizes[1] / 81;          // 2048

  const size_t wt_bytes = (size_t)nch * KPAD * sizeof(unsigned short);  // 384 KB
  if (ws_size >= wt_bytes) {
    unsigned short* WT = (unsigned short*)d_ws;
    const int cvt_threads = nch * 12;
    wt_convert_kernel<<<(cvt_threads + 255) / 256, 256, 0, stream>>>(W, WT, nch);
    dim3 grid(nch / BN, npts / BM);           // (16, 256)
    sph_mfma_kernel<<<grid, 256, 0, stream>>>(pos, WT, out, nch);
  } else {
    dim3 grid(nch / NCH_TILE, npts / NPT_TILE);
    sph_embed_kernel<<<grid, TPB, 0, stream>>>(pos, W, out, nch);
  }
}